// Round 1
// 415.398 us; speedup vs baseline: 1.0479x; 1.0479x over previous
//
#include <hip/hip_runtime.h>

#define DEV __device__ __forceinline__

typedef _Float16 half8 __attribute__((ext_vector_type(8)));
typedef _Float16 half4_t __attribute__((ext_vector_type(4)));
typedef float f32x4 __attribute__((ext_vector_type(4)));

DEV float ftanh(float x){
  float ax = fabsf(x);
  float e = __expf(-2.f*ax);
  float t = (1.f - e)/(1.f + e);
  return x < 0.f ? -t : t;
}
DEV float fsigm(float x){ return 1.f/(1.f + expf(-x)); }
DEV float wredsum(float v){
  #pragma unroll
  for (int o=32;o;o>>=1) v += __shfl_xor(v,o,64);
  return v;
}

// ---------------- graph prep ----------------
__global__ void k_zero_i32(int* __restrict__ p, int n){
  int i = blockIdx.x*256 + threadIdx.x; if (i<n) p[i]=0;
}

__global__ void k_hist2(const int* __restrict__ s1, const int* __restrict__ d1, int E1,
                        int* __restrict__ co1, int* __restrict__ ci1,
                        const int* __restrict__ s2, const int* __restrict__ d2, int E2,
                        int* __restrict__ co2, int* __restrict__ ci2){
  int e = blockIdx.x*256 + threadIdx.x;
  if (e < E1){ atomicAdd(&co1[s1[e]],1); atomicAdd(&ci1[d1[e]],1); }
  int f = e - E1;
  if (f >= 0 && f < E2){ atomicAdd(&co2[s2[f]],1); atomicAdd(&ci2[d2[f]],1); }
}

__global__ void k_scan2(const int* __restrict__ c1, int n1, int* __restrict__ r1,
                        const int* __restrict__ c2, int n2, int* __restrict__ r2){
  __shared__ int sm[1024];
  const int* cnt = blockIdx.x ? c2 : c1;
  int*       row = blockIdx.x ? r2 : r1;
  int n          = blockIdx.x ? n2 : n1;
  int t = threadIdx.x;
  int per = n/1024 + 1;
  int st = t*per;
  int s = 0;
  for (int i=st;i<st+per;++i) if (i<n) s += cnt[i];
  sm[t]=s; __syncthreads();
  for (int o=1;o<1024;o<<=1){
    int v = (t>=o)? sm[t-o]:0;
    __syncthreads();
    sm[t] += v;
    __syncthreads();
  }
  int base = sm[t]-s;
  for (int i=st;i<st+per;++i){
    if (i<=n) row[i]=base;
    if (i<n) base += cnt[i];
  }
}

__global__ void k_scale2(const int* __restrict__ co1, const int* __restrict__ ci1, int n1,
                         float* __restrict__ os1, float* __restrict__ is1,
                         const int* __restrict__ co2, const int* __restrict__ ci2, int n2,
                         float* __restrict__ os2, float* __restrict__ is2){
  int i = blockIdx.x*256+threadIdx.x;
  if (i<n1){
    int a = co1[i] > 1 ? co1[i] : 1;
    int b = ci1[i] > 1 ? ci1[i] : 1;
    os1[i] = 1.f/sqrtf((float)a);
    is1[i] = 1.f/sqrtf((float)b);
  }
  int j = i - n1;
  if (j>=0 && j<n2){
    int a = co2[j] > 1 ? co2[j] : 1;
    int b = ci2[j] > 1 ? ci2[j] : 1;
    os2[j] = 1.f/sqrtf((float)a);
    is2[j] = 1.f/sqrtf((float)b);
  }
}

__global__ void k_scatter2(const int* __restrict__ s1, const int* __restrict__ d1, int E1,
                           const int* __restrict__ row1, int* __restrict__ cur1, int* __restrict__ csr1,
                           const int* __restrict__ s2, const int* __restrict__ d2, int E2,
                           const int* __restrict__ row2, int* __restrict__ cur2, int* __restrict__ csr2){
  int e = blockIdx.x*256+threadIdx.x;
  if (e<E1){ int d=d1[e]; int p=atomicAdd(&cur1[d],1); csr1[row1[d]+p]=s1[e]; }
  int f = e - E1;
  if (f>=0 && f<E2){ int d=d2[f]; int p=atomicAdd(&cur2[d],1); csr2[row2[d]+p]=s2[f]; }
}

__global__ void k_goff2(const int* __restrict__ g1, int n1, int* __restrict__ o1,
                        const int* __restrict__ g2, int n2, int* __restrict__ o2, int B){
  int t = threadIdx.x;
  const int* gid = (t>=256)? g2 : g1;
  int*      goff = (t>=256)? o2 : o1;
  int n          = (t>=256)? n2 : n1;
  int q = t & 255;
  if (q<=B){
    int lo=0, hi=n;
    while (lo<hi){ int mid=(lo+hi)>>1; if (gid[mid]<q) lo=mid+1; else hi=mid; }
    goff[q]=lo;
  }
}

// gather aggregation with split-f16 output planes:
// acc[node] = sum_{e in in(node)} x[src_e] * (osc? osc[src_e] : 1) ; oh=f16(acc), ol=f16(acc-oh)
__global__ void k_agg_h(const float* __restrict__ x, int ldx, const float* __restrict__ osc,
                        const int* __restrict__ row, const int* __restrict__ csr,
                        _Float16* __restrict__ oh, _Float16* __restrict__ ol, int n, int f4shift){
  int F4 = 1<<f4shift;
  int node = blockIdx.x*(256>>f4shift) + (threadIdx.x>>f4shift);
  if (node>=n) return;
  int fc = threadIdx.x & (F4-1);
  int F = F4<<2;
  int rs=row[node], re=row[node+1];
  float ax=0, ay=0, az=0, aw=0;
  if (osc){
    for (int e=rs;e<re;++e){
      int s = csr[e];
      float sc = osc[s];
      const float4 v = *(const float4*)(x + (size_t)s*ldx + (fc<<2));
      ax += sc*v.x; ay += sc*v.y; az += sc*v.z; aw += sc*v.w;
    }
  } else {
    int e = rs;
    for (; e+1<re; e+=2){
      int s0 = csr[e], s1 = csr[e+1];
      const float4 v0 = *(const float4*)(x + (size_t)s0*ldx + (fc<<2));
      const float4 v1 = *(const float4*)(x + (size_t)s1*ldx + (fc<<2));
      ax += v0.x+v1.x; ay += v0.y+v1.y; az += v0.z+v1.z; aw += v0.w+v1.w;
    }
    if (e<re){
      int s0 = csr[e];
      const float4 v0 = *(const float4*)(x + (size_t)s0*ldx + (fc<<2));
      ax += v0.x; ay += v0.y; az += v0.z; aw += v0.w;
    }
  }
  half4_t hv, lv;
  hv.x = (_Float16)ax; lv.x = (_Float16)(ax - (float)hv.x);
  hv.y = (_Float16)ay; lv.y = (_Float16)(ay - (float)hv.y);
  hv.z = (_Float16)az; lv.z = (_Float16)(az - (float)hv.z);
  hv.w = (_Float16)aw; lv.w = (_Float16)(aw - (float)hv.w);
  size_t o = (size_t)node*F + (fc<<2);
  *(half4_t*)(oh + o) = hv;
  *(half4_t*)(ol + o) = lv;
}

// pack 4 GraphConv weights (fp32 [K][N]) into split-f16 hi/lo, k8-packed layout:
// element (k,n) -> plane[ ((k>>3)*N + n)*8 + (k&7) ]
__global__ void k_wpack4(const float* __restrict__ W0, const float* __restrict__ W1,
                         const float* __restrict__ W2, const float* __restrict__ W3,
                         _Float16* __restrict__ h0, _Float16* __restrict__ l0,
                         _Float16* __restrict__ h1, _Float16* __restrict__ l1,
                         _Float16* __restrict__ h2, _Float16* __restrict__ l2,
                         _Float16* __restrict__ h3, _Float16* __restrict__ l3){
  int w = blockIdx.y;
  const float* W = (w==0)?W0:(w==1)?W1:(w==2)?W2:W3;
  _Float16* oh = (w==0)?h0:(w==1)?h1:(w==2)?h2:h3;
  _Float16* ol = (w==0)?l0:(w==1)?l1:(w==2)?l2:l3;
  int K   = (w&1)? 256 : 128;
  int nsh = (w&1)? 9 : 8;
  int i = blockIdx.x*256 + threadIdx.x;
  if (i >= (K<<nsh)) return;
  int k = i >> nsh, n = i & ((1<<nsh)-1);
  float v = W[i];
  _Float16 h = (_Float16)v;
  _Float16 l = (_Float16)(v - (float)h);
  size_t p = (((size_t)(k>>3)<<nsh) + n)*8 + (k&7);
  oh[p] = h; ol[p] = l;
}

// ------- k_gconv_mfma: dual-side split-f16 MFMA GEMM.
// C = Ahi*Bhi + Alo*Bhi + Ahi*Blo (fp32 MFMA accum), 128x128 tile, 4 waves (2x2),
// BK=32 using v_mfma_f32_16x16x32_f16, double-buffered LDS, reg-prefetch staging,
// XCD-bijective swizzle. Epilogue: acc*rs + bias, optional relu, optional post-scale.
// A planes: row-major [M][K] f16. B planes: k8-packed [K/8][N][8] f16.
__global__ __launch_bounds__(256)
void k_gconv_mfma(const _Float16* __restrict__ Ah0, const _Float16* __restrict__ Al0,
                  const _Float16* __restrict__ Ah1, const _Float16* __restrict__ Al1,
                  const _Float16* __restrict__ Bh0, const _Float16* __restrict__ Bl0,
                  const _Float16* __restrict__ Bh1, const _Float16* __restrict__ Bl1,
                  float* __restrict__ C0, float* __restrict__ C1, int ldc,
                  int M0, int M1, int N, int K,
                  const float* __restrict__ rs0, const float* __restrict__ rs1,
                  const float* __restrict__ bi0, const float* __restrict__ bi1, int relu,
                  const float* __restrict__ po0, const float* __restrict__ po1)
{
  __shared__ __align__(16) _Float16 As[2][4096];   // [kb(4)][m(128)][8]
  __shared__ __align__(16) _Float16 Bs[2][4096];   // [kb(4)][n(128)][8]

  const int gx = gridDim.x, gxy = gridDim.x*gridDim.y;
  const int nwg = gxy*2;
  int fid = blockIdx.x + gx*blockIdx.y + gxy*blockIdx.z;
  int q = nwg>>3, r = nwg&7;
  int xcd = fid & 7, idx = fid >> 3;
  int sid = (xcd<r ? xcd*(q+1) : r*(q+1)+(xcd-r)*q) + idx;
  const int z  = sid / gxy;  int rem = sid - z*gxy;
  const int by = rem / gx,  bx = rem - by*gx;

  const _Float16* Ah = z ? Ah1 : Ah0;
  const _Float16* Al = z ? Al1 : Al0;
  const _Float16* Bh = z ? Bh1 : Bh0;
  const _Float16* Bl = z ? Bl1 : Bl0;
  float*       C  = z ? C1 : C0;
  const float* rsc = z ? rs1 : rs0;
  const float* bia = z ? bi1 : bi0;
  const float* po  = z ? po1 : po0;
  const int M = z ? M1 : M0;

  const int row0 = by << 7;
  const int col0 = bx << 7;
  if (row0 >= ((M+127)&~127)) return;

  const int tid = threadIdx.x;
  // A staging: chunk c in [0,512): m=c>>2, kb=c&3 ; this thread does c=tid (m) and c=tid+256 (m+64)
  const int am  = tid >> 2;
  const int akb = tid & 3;
  // B staging: chunk c: n=c&127, kb=c>>7 ; this thread does c=tid (kb 0/1) and c=tid+256 (kb 2/3)
  const int bn  = tid & 127;
  const int bkb = tid >> 7;
  // wave / fragment mapping
  const int wid = tid >> 6, lane = tid & 63;
  const int wr = wid >> 1, wc = wid & 1;
  const int lr = lane & 15, lg = lane >> 4;

  const size_t ldb8 = (size_t)N * 8;
  f32x4 acc[4][4] = {};

  const int kpt = K >> 5;     // K-steps per term
  const int nt  = 3 * kpt;    // total K-steps (hi*hi, lo*hi, hi*lo)

  half8 ga0, ga1, gb0, gb1;
  {
    const _Float16* Ap = Ah + (size_t)(row0 + am) * K + (akb<<3);
    ga0 = *(const half8*)(Ap);
    ga1 = *(const half8*)(Ap + (size_t)64 * K);
    const _Float16* Bp = Bh + (size_t)bkb * ldb8 + (size_t)(col0 + bn) * 8;
    gb0 = *(const half8*)(Bp);
    gb1 = *(const half8*)(Bp + 2*ldb8);
  }
  *(half8*)&As[0][(akb*128 + am)*8]        = ga0;
  *(half8*)&As[0][(akb*128 + am + 64)*8]   = ga1;
  *(half8*)&Bs[0][(bkb*128 + bn)*8]        = gb0;
  *(half8*)&Bs[0][((bkb+2)*128 + bn)*8]    = gb1;
  __syncthreads();

  int term = 0, kk = 32;    // coordinates of the NEXT tile (t+1)
  if (kk == K){ kk = 0; term = 1; }
  for (int t = 0; t < nt; ++t){
    const int cb = t & 1;
    if (t + 1 < nt){
      const _Float16* Asrc = (term == 1) ? Al : Ah;
      const _Float16* Bsrc = (term == 2) ? Bl : Bh;
      const _Float16* Ap = Asrc + (size_t)(row0 + am) * K + kk + (akb<<3);
      ga0 = *(const half8*)(Ap);
      ga1 = *(const half8*)(Ap + (size_t)64 * K);
      const _Float16* Bp = Bsrc + (size_t)((kk>>3) + bkb) * ldb8 + (size_t)(col0 + bn) * 8;
      gb0 = *(const half8*)(Bp);
      gb1 = *(const half8*)(Bp + 2*ldb8);
      kk += 32; if (kk == K){ kk = 0; ++term; }
    }
    {
      const _Float16* Abase = &As[cb][((lg<<7) + (wr<<6) + lr)<<3];
      const _Float16* Bbase = &Bs[cb][((lg<<7) + (wc<<6) + lr)<<3];
      half8 af[4], bf[4];
      #pragma unroll
      for (int i=0;i<4;++i){
        af[i] = *(const half8*)(Abase + i*128);
        bf[i] = *(const half8*)(Bbase + i*128);
      }
      #pragma unroll
      for (int mi=0; mi<4; ++mi){
        #pragma unroll
        for (int ni=0; ni<4; ++ni){
          acc[mi][ni] = __builtin_amdgcn_mfma_f32_16x16x32_f16(af[mi], bf[ni], acc[mi][ni], 0, 0, 0);
        }
      }
    }
    if (t + 1 < nt){
      const int nb = cb ^ 1;
      *(half8*)&As[nb][(akb*128 + am)*8]      = ga0;
      *(half8*)&As[nb][(akb*128 + am + 64)*8] = ga1;
      *(half8*)&Bs[nb][(bkb*128 + bn)*8]      = gb0;
      *(half8*)&Bs[nb][((bkb+2)*128 + bn)*8]  = gb1;
    }
    __syncthreads();
  }

  // epilogue: D row = row0 + wr*64 + mi*16 + lg*4 + j ; col = col0 + wc*64 + ni*16 + lr
  #pragma unroll
  for (int ni = 0; ni < 4; ++ni){
    int cc = col0 + (wc<<6) + (ni<<4) + lr;
    float bv = bia ? bia[cc] : 0.f;
    #pragma unroll
    for (int mi = 0; mi < 4; ++mi){
      int rbase = row0 + (wr<<6) + (mi<<4) + (lg<<2);
      #pragma unroll
      for (int j = 0; j < 4; ++j){
        int rr = rbase + j;
        if (rr < M){
          float rs_ = rsc ? rsc[rr] : 1.f;
          float v = acc[mi][ni][j]*rs_ + bv;
          if (relu) v = fmaxf(v, 0.f);
          if (po) v *= po[rr];
          C[(size_t)rr*ldc + cc] = v;
        }
      }
    }
  }
}

// ------- k_gemmsk: skinny NT GEMM, M=128 x 64-col tile, dbuf LDS, split-K,
// optional dual-side via blockIdx.y. Partials P[(side*splits+z)][M][N].
__global__ __launch_bounds__(256)
void k_gemmsk(const float* __restrict__ Ab, size_t AsideOff, int lda,
              const float* __restrict__ Bm, int ldb,
              float* __restrict__ P, int M, int N, int kchunk)
{
  __shared__ float As[2][16][132];
  __shared__ float Bs[2][16][68];
  const int tid = threadIdx.x;
  const int col0 = (int)blockIdx.x << 6;
  const int kbeg = (int)blockIdx.z * kchunk;
  const float* A = Ab + (size_t)blockIdx.y * AsideOff;
  const int ar = tid >> 1, ak = (tid & 1) << 3;
  const int br = tid >> 2, bk = (tid & 3) << 2;
  const int tx = tid & 15, ty = tid >> 4;
  const float* Arow = A + (size_t)ar * lda + kbeg + ak;
  const float* Brow = Bm + (size_t)(col0 + br) * ldb + kbeg + bk;
  float acc[8][4] = {};
  float4 a0 = *(const float4*)(Arow);
  float4 a1 = *(const float4*)(Arow + 4);
  float4 b0 = *(const float4*)(Brow);
  As[0][ak+0][ar]=a0.x; As[0][ak+1][ar]=a0.y; As[0][ak+2][ar]=a0.z; As[0][ak+3][ar]=a0.w;
  As[0][ak+4][ar]=a1.x; As[0][ak+5][ar]=a1.y; As[0][ak+6][ar]=a1.z; As[0][ak+7][ar]=a1.w;
  Bs[0][bk+0][br]=b0.x; Bs[0][bk+1][br]=b0.y; Bs[0][bk+2][br]=b0.z; Bs[0][bk+3][br]=b0.w;
  __syncthreads();
  const int nt = kchunk >> 4;
  for (int t = 0; t < nt; ++t){
    const int cb = t & 1;
    if (t + 1 < nt){
      int k0 = (t + 1) << 4;
      a0 = *(const float4*)(Arow + k0);
      a1 = *(const float4*)(Arow + k0 + 4);
      b0 = *(const float4*)(Brow + k0);
    }
    #pragma unroll
    for (int kk = 0; kk < 16; ++kk){
      float4 b4 = *(const float4*)&Bs[cb][kk][tx << 2];
      float4 a4 = *(const float4*)&As[cb][kk][ty << 3];
      float4 a5 = *(const float4*)&As[cb][kk][(ty << 3) + 4];
      acc[0][0]+=a4.x*b4.x; acc[0][1]+=a4.x*b4.y; acc[0][2]+=a4.x*b4.z; acc[0][3]+=a4.x*b4.w;
      acc[1][0]+=a4.y*b4.x; acc[1][1]+=a4.y*b4.y; acc[1][2]+=a4.y*b4.z; acc[1][3]+=a4.y*b4.w;
      acc[2][0]+=a4.z*b4.x; acc[2][1]+=a4.z*b4.y; acc[2][2]+=a4.z*b4.z; acc[2][3]+=a4.z*b4.w;
      acc[3][0]+=a4.w*b4.x; acc[3][1]+=a4.w*b4.y; acc[3][2]+=a4.w*b4.z; acc[3][3]+=a4.w*b4.w;
      acc[4][0]+=a5.x*b4.x; acc[4][1]+=a5.x*b4.y; acc[4][2]+=a5.x*b4.z; acc[4][3]+=a5.x*b4.w;
      acc[5][0]+=a5.y*b4.x; acc[5][1]+=a5.y*b4.y; acc[5][2]+=a5.y*b4.z; acc[5][3]+=a5.y*b4.w;
      acc[6][0]+=a5.z*b4.x; acc[6][1]+=a5.z*b4.y; acc[6][2]+=a5.z*b4.z; acc[6][3]+=a5.z*b4.w;
      acc[7][0]+=a5.w*b4.x; acc[7][1]+=a5.w*b4.y; acc[7][2]+=a5.w*b4.z; acc[7][3]+=a5.w*b4.w;
    }
    if (t + 1 < nt){
      const int nb = cb ^ 1;
      As[nb][ak+0][ar]=a0.x; As[nb][ak+1][ar]=a0.y; As[nb][ak+2][ar]=a0.z; As[nb][ak+3][ar]=a0.w;
      As[nb][ak+4][ar]=a1.x; As[nb][ak+5][ar]=a1.y; As[nb][ak+6][ar]=a1.z; As[nb][ak+7][ar]=a1.w;
      Bs[nb][bk+0][br]=b0.x; Bs[nb][bk+1][br]=b0.y; Bs[nb][bk+2][br]=b0.z; Bs[nb][bk+3][br]=b0.w;
    }
    __syncthreads();
  }
  float* Pz = P + (size_t)(blockIdx.y*gridDim.z + blockIdx.z) * M * N;
  #pragma unroll
  for (int i = 0; i < 8; ++i){
    int rr = (ty << 3) + i;
    float4 v = {acc[i][0], acc[i][1], acc[i][2], acc[i][3]};
    *(float4*)(Pz + (size_t)rr*N + col0 + (tx<<2)) = v;
  }
}

// sum split partials + bias (+relu)
__global__ void k_red_bias(const float* __restrict__ P, int split, int MN, int N,
                           const float* __restrict__ bias, float* __restrict__ C, int relu){
  int i = blockIdx.x*256 + threadIdx.x;
  if (i >= MN) return;
  float v = bias[i & (N-1)];
  for (int s=0;s<split;++s) v += P[(size_t)s*MN + i];
  if (relu) v = fmaxf(v, 0.f);
  C[i] = v;
}

// ---------------- block-diag interaction ----------------
__global__ __launch_bounds__(256)
void k_pairdot(const float* __restrict__ sf, const float* __restrict__ vf,
               const int* __restrict__ go1, const int* __restrict__ go2, float* __restrict__ T)
{
  __shared__ float As[16][68];
  __shared__ float Bs[16][68];
  int g = blockIdx.z;
  int it = blockIdx.y, jt = blockIdx.x;
  int gox = go1[g]; int cx = go1[g+1]-gox; if (cx>128) cx=128;
  int goy = go2[g]; int cy = go2[g+1]-goy; if (cy>128) cy=128;
  int cx64=(cx+63)&~63, cy64=(cy+63)&~63;
  int i0 = it<<6, j0 = jt<<6;
  if (i0 >= cx64 || j0 >= cy64) return;
  int tid=threadIdx.x, tx=tid&15, ty=tid>>4;
  int a_r = tid>>2, a_k=(tid&3)<<2;
  const float* Arow = sf + (size_t)(gox+i0+a_r)*1024;
  const float* Brow = vf + (size_t)(goy+j0+a_r)*1024;
  bool act = ((i0+(ty<<2)) < cx) && ((j0+(tx<<2)) < cy);
  float acc[4][4]={};
  for (int k0=0;k0<512;k0+=16){
    float4 av = *(const float4*)(Arow + k0 + a_k);
    float4 bv = *(const float4*)(Brow + k0 + a_k);
    As[a_k+0][a_r]=av.x; As[a_k+1][a_r]=av.y; As[a_k+2][a_r]=av.z; As[a_k+3][a_r]=av.w;
    Bs[a_k+0][a_r]=bv.x; Bs[a_k+1][a_r]=bv.y; Bs[a_k+2][a_r]=bv.z; Bs[a_k+3][a_r]=bv.w;
    __syncthreads();
    if (act){
      float4 a4 = *(const float4*)&As[0][ty<<2];
      float4 b4 = *(const float4*)&Bs[0][tx<<2];
      #pragma unroll
      for (int kk=0;kk<16;++kk){
        float4 na, nb;
        if (kk<15){
          na = *(const float4*)&As[kk+1][ty<<2];
          nb = *(const float4*)&Bs[kk+1][tx<<2];
        }
        acc[0][0] += a4.x*b4.x; acc[0][1] += a4.x*b4.y; acc[0][2] += a4.x*b4.z; acc[0][3] += a4.x*b4.w;
        acc[1][0] += a4.y*b4.x; acc[1][1] += a4.y*b4.y; acc[1][2] += a4.y*b4.z; acc[1][3] += a4.y*b4.w;
        acc[2][0] += a4.z*b4.x; acc[2][1] += a4.z*b4.y; acc[2][2] += a4.z*b4.z; acc[2][3] += a4.z*b4.w;
        acc[3][0] += a4.w*b4.x; acc[3][1] += a4.w*b4.y; acc[3][2] += a4.w*b4.z; acc[3][3] += a4.w*b4.w;
        if (kk<15){ a4 = na; b4 = nb; }
      }
    }
    __syncthreads();
  }
  float* Tg = T + (size_t)g*16384;
  #pragma unroll
  for (int ii=0; ii<4; ++ii){
    int gi = i0 + (ty<<2) + ii;
    int gj = j0 + (tx<<2);
    float4 v;
    v.x = (gi<cx && gj+0<cy) ? ftanh(acc[ii][0]) : 0.f;
    v.y = (gi<cx && gj+1<cy) ? ftanh(acc[ii][1]) : 0.f;
    v.z = (gi<cx && gj+2<cy) ? ftanh(acc[ii][2]) : 0.f;
    v.w = (gi<cx && gj+3<cy) ? ftanh(acc[ii][3]) : 0.f;
    *(float4*)(Tg + (size_t)gi*128 + gj) = v;
  }
}

template<bool TRANS>
__global__ __launch_bounds__(256)
void k_outapply(const float* __restrict__ T, const float* __restrict__ other,
                float* __restrict__ own, const int* __restrict__ goOwn, const int* __restrict__ goOther)
{
  __shared__ float As[16][68];
  __shared__ float Bs[16][68];
  int g = blockIdx.z;
  int r0 = (int)blockIdx.y<<6;
  int f0 = (int)blockIdx.x<<6;
  int gown = goOwn[g];   int cown = goOwn[g+1]-gown;   if (cown>128) cown=128;
  int goth = goOther[g]; int coth = goOther[g+1]-goth; if (coth>128) coth=128;
  int cr64 = (cown+63)&~63;
  if (r0 >= cr64) return;
  int K16 = (coth+15)&~15;
  const float* Tg = T + (size_t)g*16384;
  int tid=threadIdx.x, tx=tid&15, ty=tid>>4;
  bool act = (r0 + (ty<<2)) < cown;
  float acc[4][4]={};
  for (int ks=0; ks<K16; ks+=16){
    if (!TRANS){
      int rr = tid>>2, k4 = (tid&3)<<2;
      float4 av = *(const float4*)(Tg + (size_t)(r0+rr)*128 + ks + k4);
      As[k4+0][rr]=av.x; As[k4+1][rr]=av.y; As[k4+2][rr]=av.z; As[k4+3][rr]=av.w;
    } else {
      int kk = tid>>4, r4 = (tid&15)<<2;
      *(float4*)&As[kk][r4] = *(const float4*)(Tg + (size_t)(ks+kk)*128 + r0 + r4);
    }
    int bk = tid>>4, bf = (tid&15)<<2;
    *(float4*)&Bs[bk][bf] = *(const float4*)(other + (size_t)(goth+ks+bk)*1024 + f0 + bf);
    __syncthreads();
    if (act){
      float4 a4 = *(const float4*)&As[0][ty<<2];
      float4 b4 = *(const float4*)&Bs[0][tx<<2];
      #pragma unroll
      for (int kk=0;kk<16;++kk){
        float4 na, nb;
        if (kk<15){
          na = *(const float4*)&As[kk+1][ty<<2];
          nb = *(const float4*)&Bs[kk+1][tx<<2];
        }
        acc[0][0] += a4.x*b4.x; acc[0][1] += a4.x*b4.y; acc[0][2] += a4.x*b4.z; acc[0][3] += a4.x*b4.w;
        acc[1][0] += a4.y*b4.x; acc[1][1] += a4.y*b4.y; acc[1][2] += a4.y*b4.z; acc[1][3] += a4.y*b4.w;
        acc[2][0] += a4.z*b4.x; acc[2][1] += a4.z*b4.y; acc[2][2] += a4.z*b4.z; acc[2][3] += a4.z*b4.w;
        acc[3][0] += a4.w*b4.x; acc[3][1] += a4.w*b4.y; acc[3][2] += a4.w*b4.z; acc[3][3] += a4.w*b4.w;
        if (kk<15){ a4 = na; b4 = nb; }
      }
    }
    __syncthreads();
  }
  #pragma unroll
  for (int ii=0; ii<4; ++ii){
    int rr = r0 + (ty<<2) + ii;
    if (rr < cown){
      float4 v = {acc[ii][0],acc[ii][1],acc[ii][2],acc[ii][3]};
      *(float4*)(own + (size_t)(gown+rr)*1024 + 512 + f0 + (tx<<2)) = v;
    }
  }
}

// ---------------- Set2Set ----------------
__global__ void k_lstm1(const float* __restrict__ bih, const float* __restrict__ bhh,
                        float* __restrict__ c1, float* __restrict__ h1){
  int j = blockIdx.x*256 + threadIdx.x;
  if (j >= 1024) return;
  float gi = bih[j]        + bhh[j];
  float gg = bih[j+2048]   + bhh[j+2048];
  float go = bih[j+3072]   + bhh[j+3072];
  float cc = fsigm(gi)*ftanh(gg);
  c1[j] = cc;
  h1[j] = fsigm(go)*ftanh(cc);
}

__global__ void k_gemv_u(const float* __restrict__ Wih, const float* __restrict__ Whh,
                         const float* __restrict__ bih, const float* __restrict__ bhh,
                         const float* __restrict__ h1, float* __restrict__ u){
  int w = (blockIdx.x*256 + threadIdx.x)>>6;
  int lane = threadIdx.x & 63;
  if (w >= 4096) return;
  const float* wi = Wih + (size_t)w*2048;
  const float* wh = Whh + (size_t)w*1024;
  float acc = 0.f;
  #pragma unroll
  for (int qq=0;qq<4;++qq){
    int o = qq*256 + (lane<<2);
    float4 hv = *(const float4*)(h1 + o);
    float4 a  = *(const float4*)(wi + o);
    float4 b  = *(const float4*)(wh + o);
    acc += hv.x*(a.x+b.x) + hv.y*(a.y+b.y) + hv.z*(a.z+b.z) + hv.w*(a.w+b.w);
  }
  acc = wredsum(acc);
  if (lane==0) u[w] = acc + bih[w] + bhh[w];
}

// fused attention, dual-side (blockIdx.y): online segment softmax + weighted sum
__global__ __launch_bounds__(256)
void k_attn(const float* __restrict__ sf, const float* __restrict__ vf,
            const int* __restrict__ go1, const int* __restrict__ go2,
            const float* __restrict__ hbase, size_t hSideOff, int hstride,
            float* __restrict__ outbase, size_t oSideOff, int ldout)
{
  __shared__ float hs[1024];
  __shared__ float ech[1024];
  __shared__ float red[8];
  int side = blockIdx.y;
  const float* x = side? vf : sf;
  const int* goff = side? go2 : go1;
  const float* hsrc = hbase + (size_t)side*hSideOff;
  float* outp = outbase + (size_t)side*oSideOff;
  int b = blockIdx.x, t = threadIdx.x;
  int i0 = goff[b], i1 = goff[b+1];
  int lane = t & 63, wv = t >> 6;
  { float4 hv = *(const float4*)(hsrc + (size_t)b*hstride + (t<<2));
    *(float4*)&hs[t<<2] = hv; }
  __syncthreads();
  float m = -3.0e38f, s = 0.f;
  float ax=0, ay=0, az=0, aw=0;
  for (int c = i0; c < i1; c += 1024){
    int ce = c + 1024; if (ce > i1) ce = i1;
    int n = ce - c;
    float wmax = -3.0e38f;
    for (int i = c + wv; i < ce; i += 4){
      const float* xr = x + (size_t)i*1024;
      float d = 0.f;
      #pragma unroll
      for (int qq=0;qq<4;++qq){
        int o = qq*256 + (lane<<2);
        float4 xv = *(const float4*)(xr+o);
        float4 h4 = *(const float4*)&hs[o];
        d += xv.x*h4.x + xv.y*h4.y + xv.z*h4.z + xv.w*h4.w;
      }
      d = wredsum(d);
      if (lane==0) ech[i-c] = d;
      wmax = fmaxf(wmax, d);
    }
    if (lane==0) red[wv] = wmax;
    __syncthreads();
    float cm = fmaxf(fmaxf(red[0],red[1]), fmaxf(red[2],red[3]));
    float nm = fmaxf(m, cm);
    float scale = __expf(m - nm);
    s *= scale; ax*=scale; ay*=scale; az*=scale; aw*=scale;
    float ps = 0.f;
    for (int k = t; k < n; k += 256) ps += __expf(ech[k]-nm);
    ps = wredsum(ps);
    __syncthreads();
    if (lane==0) red[wv] = ps;
    __syncthreads();
    s += red[0]+red[1]+red[2]+red[3];
    for (int k = 0; k < n; ++k){
      float w = __expf(ech[k]-nm);
      float4 xv = *(const float4*)(x + (size_t)(c+k)*1024 + (t<<2));
      ax += w*xv.x; ay += w*xv.y; az += w*xv.z; aw += w*xv.w;
    }
    m = nm;
    __syncthreads();
  }
  float inv = (i1>i0 && s>0.f) ? 1.f/s : 0.f;
  float4 o = {ax*inv, ay*inv, az*inv, aw*inv};
  *(float4*)(outp + (size_t)b*ldout + (t<<2)) = o;
}

// LSTM iter2 (dual-side via blockIdx.y): sum split gate partials + u, cell/hidden
__global__ void k_lstm2_red(const float* __restrict__ Pb, size_t PsideOff, int split,
                            const float* __restrict__ u, const float* __restrict__ c1,
                            float* __restrict__ z, int B){
  int idx = blockIdx.x*256 + threadIdx.x;
  if (idx >= B*1024) return;
  int side = blockIdx.y;
  const float* P = Pb + (size_t)side*PsideOff;
  int b = idx >> 10, j = idx & 1023;
  float gi=u[j], gf=u[j+1024], gg=u[j+2048], go=u[j+3072];
  const float* g = P + (size_t)b*4096;
  for (int s=0;s<split;++s){
    const float* gs = g + (size_t)s*B*4096;
    gi += gs[j]; gf += gs[j+1024]; gg += gs[j+2048]; go += gs[j+3072];
  }
  float cc = fsigm(gf)*c1[j] + fsigm(gi)*ftanh(gg);
  z[(size_t)b*4096 + side*2048 + j] = fsigm(go)*ftanh(cc);
}

__global__ void k_fc3(const float* __restrict__ z2, const float* __restrict__ w3,
                      const float* __restrict__ b3, float* __restrict__ out, int B){
  int wv = (blockIdx.x*256+threadIdx.x)>>6;
  int lane = threadIdx.x & 63;
  if (wv >= B) return;
  const float* zr = z2 + (size_t)wv*512;
  float acc=0.f;
  #pragma unroll
  for (int qq=0;qq<2;++qq){
    int o = qq*256 + (lane<<2);
    float4 a  = *(const float4*)(zr + o);
    float4 ww = *(const float4*)(w3 + o);
    acc += a.x*ww.x + a.y*ww.y + a.z*ww.z + a.w*ww.w;
  }
  acc = wredsum(acc);
  if (lane==0) out[wv] = acc + b3[0];
}

// ---------------- driver ----------------
extern "C" void kernel_launch(void* const* d_in, const int* in_sizes, int n_in,
                              void* d_out, int out_size, void* d_ws, size_t ws_size,
                              hipStream_t stream)
{
  const float* x1  = (const float*)d_in[0];
  const float* x2  = (const float*)d_in[1];
  const int* src1  = (const int*)d_in[2];
  const int* dst1  = (const int*)d_in[3];
  const int* src2  = (const int*)d_in[4];
  const int* dst2  = (const int*)d_in[5];
  const int* gid1  = (const int*)d_in[6];
  const int* gid2  = (const int*)d_in[7];
  const float* Wg1 = (const float*)d_in[8];  const float* bg1 = (const float*)d_in[9];
  const float* Wg2 = (const float*)d_in[10]; const float* bg2 = (const float*)d_in[11];
  const float* Wg3 = (const float*)d_in[12]; const float* bg3 = (const float*)d_in[13];
  const float* Wg4 = (const float*)d_in[14]; const float* bg4 = (const float*)d_in[15];
  const float* Wih = (const float*)d_in[16]; const float* Whh = (const float*)d_in[17];
  const float* bih = (const float*)d_in[18]; const float* bhh = (const float*)d_in[19];
  const float* Wf1 = (const float*)d_in[20]; const float* bf1 = (const float*)d_in[21];
  const float* Wf2 = (const float*)d_in[22]; const float* bf2 = (const float*)d_in[23];
  const float* Wf3 = (const float*)d_in[24]; const float* bf3 = (const float*)d_in[25];
  float* out = (float*)d_out;

  const int N1 = in_sizes[0]/128;
  const int N2 = in_sizes[1]/128;
  const int E1 = in_sizes[2];
  const int E2 = in_sizes[4];
  const int B  = out_size;            // 128
  const int NM = N1>N2?N1:N2;

  char* base = (char*)d_ws; size_t off=0;
  auto alloc = [&](size_t bytes)->void*{ void* p = base+off; off += (bytes+255)&~(size_t)255; return p; };

  int* zr   = (int*)alloc(sizeof(int)*(size_t)(3*N1+3*N2));
  int* co1=zr, *ci1=zr+N1, *cur1=zr+2*N1;
  int* co2=zr+3*N1, *ci2=zr+3*N1+N2, *cur2=zr+3*N1+2*N2;
  int* row1 = (int*)alloc(sizeof(int)*(size_t)(N1+1));
  int* row2 = (int*)alloc(sizeof(int)*(size_t)(N2+1));
  int* csr1 = (int*)alloc(sizeof(int)*(size_t)E1);
  int* csr2 = (int*)alloc(sizeof(int)*(size_t)E2);
  int* go1  = (int*)alloc(sizeof(int)*(size_t)(B+1));
  int* go2  = (int*)alloc(sizeof(int)*(size_t)(B+1));
  float* os1 = (float*)alloc(sizeof(float)*(size_t)N1);
  float* is1 = (float*)alloc(sizeof(float)*(size_t)N1);
  float* os2 = (float*)alloc(sizeof(float)*(size_t)N2);
  float* is2 = (float*)alloc(sizeof(float)*(size_t)N2);
  _Float16* a1h = (_Float16*)alloc(sizeof(_Float16)*(size_t)(NM+128)*256);
  _Float16* a1l = (_Float16*)alloc(sizeof(_Float16)*(size_t)(NM+128)*256);
  _Float16* a2h = (_Float16*)alloc(sizeof(_Float16)*(size_t)(NM+128)*256);
  _Float16* a2l = (_Float16*)alloc(sizeof(_Float16)*(size_t)(NM+128)*256);
  _Float16* wg1h = (_Float16*)alloc(sizeof(_Float16)*32768);
  _Float16* wg1l = (_Float16*)alloc(sizeof(_Float16)*32768);
  _Float16* wg2h = (_Float16*)alloc(sizeof(_Float16)*131072);
  _Float16* wg2l = (_Float16*)alloc(sizeof(_Float16)*131072);
  _Float16* wg3h = (_Float16*)alloc(sizeof(_Float16)*32768);
  _Float16* wg3l = (_Float16*)alloc(sizeof(_Float16)*32768);
  _Float16* wg4h = (_Float16*)alloc(sizeof(_Float16)*131072);
  _Float16* wg4l = (_Float16*)alloc(sizeof(_Float16)*131072);
  float* sf  = (float*)alloc(sizeof(float)*(size_t)(N1+128)*1024);
  float* vf  = (float*)alloc(sizeof(float)*(size_t)(N2+128)*1024);
  float* h1 = (float*)alloc(sizeof(float)*1024);
  float* c1 = (float*)alloc(sizeof(float)*1024);
  float* u  = (float*)alloc(sizeof(float)*4096);
  float* r1 = (float*)alloc(sizeof(float)*(size_t)2*B*1024);
  float* z1 = (float*)alloc(sizeof(float)*(size_t)B*1024);
  float* z2 = (float*)alloc(sizeof(float)*(size_t)B*512);
  float* z  = (float*)alloc(sizeof(float)*(size_t)B*4096);
  float* T  = (float*)alloc(sizeof(float)*(size_t)B*16384);
  float* Pbuf = (float*)alloc(sizeof(float)*(size_t)16*B*1024*4); // partials (33.5 MB)
  if (off > ws_size) return;

  // hbuf regions live inside sf/vf cols [512,768) (stride 1024), overwritten later by outapply
  float* hb1 = sf + 512;
  float* hb2 = vf + 512;

  dim3 blk(256);

  // --- weight split-f16 pack (independent of graph prep) ---
  k_wpack4<<<dim3(512,4),blk,0,stream>>>(Wg1,Wg2,Wg3,Wg4,
                                         wg1h,wg1l, wg2h,wg2l, wg3h,wg3l, wg4h,wg4l);

  // --- prep ---
  k_zero_i32<<<(3*N1+3*N2+255)/256, blk, 0, stream>>>(zr, 3*N1+3*N2);
  k_hist2<<<(E1+E2+255)/256, blk, 0, stream>>>(src1,dst1,E1,co1,ci1, src2,dst2,E2,co2,ci2);
  k_scan2<<<2,1024,0,stream>>>(ci1,N1,row1, ci2,N2,row2);
  k_scale2<<<(N1+N2+255)/256,blk,0,stream>>>(co1,ci1,N1,os1,is1, co2,ci2,N2,os2,is2);
  k_scatter2<<<(E1+E2+255)/256,blk,0,stream>>>(src1,dst1,E1,row1,cur1,csr1, src2,dst2,E2,row2,cur2,csr2);
  k_goff2<<<1,512,0,stream>>>(gid1,N1,go1, gid2,N2,go2, B);

  // --- GraphConv: agg both sides (split-f16 out), dual MFMA GEMM L1 (post=os),
  //     agg (no scale), dual MFMA GEMM L2 ---
  int gy = (NM+127)/128;
  k_agg_h<<<(N1+7)/8,blk,0,stream>>>(x1,128, os1,row1,csr1, a1h,a1l, N1,5);
  k_agg_h<<<(N2+7)/8,blk,0,stream>>>(x2,128, os2,row2,csr2, a2h,a2l, N2,5);
  k_gconv_mfma<<<dim3(2,gy,2),blk,0,stream>>>(a1h,a1l, a2h,a2l,
                                              wg1h,wg1l, wg3h,wg3l,
                                              hb1,hb2,1024, N1,N2, 256,128,
                                              is1,is2, bg1,bg3, 1, os1,os2);
  k_agg_h<<<(N1+3)/4,blk,0,stream>>>(hb1,1024, nullptr,row1,csr1, a1h,a1l, N1,6);
  k_agg_h<<<(N2+3)/4,blk,0,stream>>>(hb2,1024, nullptr,row2,csr2, a2h,a2l, N2,6);
  k_gconv_mfma<<<dim3(4,gy,2),blk,0,stream>>>(a1h,a1l, a2h,a2l,
                                              wg2h,wg2l, wg4h,wg4l,
                                              sf,vf,1024, N1,N2, 512,256,
                                              is1,is2, bg2,bg4, 0, nullptr,nullptr);

  // --- block-diagonal interaction ---
  k_pairdot<<<dim3(2,2,B),blk,0,stream>>>(sf,vf,go1,go2,T);
  k_outapply<false><<<dim3(8,2,B),blk,0,stream>>>(T,vf,sf,go1,go2);
  k_outapply<true ><<<dim3(8,2,B),blk,0,stream>>>(T,sf,vf,go2,go1);

  // --- Set2Set (sides merged per stage) ---
  k_lstm1<<<4,blk,0,stream>>>(bih,bhh,c1,h1);
  k_gemv_u<<<1024,blk,0,stream>>>(Wih,Whh,bih,bhh,h1,u);

  // iter1 attention (shared h1), both sides
  k_attn<<<dim3(B,2),blk,0,stream>>>(sf,vf,go1,go2, h1,0,0, r1,(size_t)B*1024,1024);
  // gates = r1 @ Wih[:,1024:].T, both sides, split-K 4 x chunk 256
  k_gemmsk<<<dim3(64,2,4),blk,0,stream>>>(r1,(size_t)B*1024,1024, Wih+1024,2048, Pbuf, 128,4096,256);
  k_lstm2_red<<<dim3((B*1024+255)/256,2),blk,0,stream>>>(Pbuf,(size_t)4*B*4096,4, u,c1, z,B);
  // iter2 attention with per-graph h2 (in z), both sides
  k_attn<<<dim3(B,2),blk,0,stream>>>(sf,vf,go1,go2, z,2048,4096, z+1024,2048,4096);

  // --- MLP head ---
  k_gemmsk<<<dim3(16,1,16),blk,0,stream>>>(z,0,4096, Wf1,4096, Pbuf, 128,1024,256);
  k_red_bias<<<(B*1024+255)/256,blk,0,stream>>>(Pbuf,16,B*1024,1024,bf1,z1,1);
  k_gemmsk<<<dim3(8,1,8),blk,0,stream>>>(z1,0,1024, Wf2,1024, Pbuf, 128,512,128);
  k_red_bias<<<(B*512+255)/256,blk,0,stream>>>(Pbuf,8,B*512,512,bf2,z2,1);
  k_fc3<<<(B*64+255)/256,blk,0,stream>>>(z2,Wf3,bf3,out,B);
}